// Round 18
// baseline (253.864 us; speedup 1.0000x reference)
//
#include <hip/hip_runtime.h>
#include <hip/hip_bf16.h>
#include <cstddef>

#define B_ 16
#define T_ 64
#define N_ 1024
#define D_ 32
#define H_ 64
#define C_ 32
#define O_ 12

typedef __attribute__((ext_vector_type(8))) short bf16x8;
typedef __attribute__((ext_vector_type(4))) float f32x4;
#define MFMA16(a,b,c) __builtin_amdgcn_mfma_f32_16x16x32_bf16(a,b,c,0,0,0)

__device__ __forceinline__ float d_tanhf(float v){ float e = __expf(2.f*v); return 1.f - 2.f/(e + 1.f); }
__device__ __forceinline__ float d_sigmf(float v){ return 1.f/(1.f + __expf(-v)); }
__device__ __forceinline__ short f2bs(float f){
  __hip_bfloat16 h = __float2bfloat16(f);
  union { __hip_bfloat16 b; short s; } u; u.b = h; return u.s;
}
__device__ __forceinline__ unsigned int packbf(float lo, float hi){
  return (unsigned int)(unsigned short)f2bs(lo) | ((unsigned int)(unsigned short)f2bs(hi) << 16);
}

// ---------------- K0: transpose conv weights to lane-major [(lay*2+fg)*768 + qq*32 + c] ----------------
__global__ __launch_bounds__(256) void k_wt(const float* __restrict__ fw1, const float* __restrict__ gw1,
                                            const float* __restrict__ fw2, const float* __restrict__ gw2,
                                            const float* __restrict__ fw3, const float* __restrict__ gw3,
                                            float4* __restrict__ wT)
{
  int i = blockIdx.x*256 + threadIdx.x;   // 0..4607
  if (i >= 4608) return;
  int t = i / 768;
  int r = i - t*768;
  int c = r & 31;
  int qq = r >> 5;
  const float* src = (t==0)?fw1 : (t==1)?gw1 : (t==2)?fw2 : (t==3)?gw2 : (t==4)?fw3 : gw3;
  wT[t*768 + r] = reinterpret_cast<const float4*>(src)[c*24 + qq];
}

// ---------------- K1: Ubf[b,n,0:64]=bf16(m1), [64:128]=bf16(m2) ----------------
__global__ __launch_bounds__(128) void k_u(const float* __restrict__ x,
    const float* __restrict__ w1, const float* __restrict__ b1,
    const float* __restrict__ w2, const float* __restrict__ b2,
    unsigned short* __restrict__ Ubf)
{
  int row = blockIdx.x;
  int b = row & 15, n = row >> 4;
  int t = threadIdx.x;
  int hh = t & (H_-1), which = t >> 6;
  __shared__ float xl[D_];
  if (t < D_) xl[t] = x[(((size_t)b*T_ + (T_-1))*N_ + n)*D_ + t];
  __syncthreads();
  const float* w  = which ? w2 : w1;
  const float* bi = which ? b2 : b1;
  float acc = bi[hh];
  #pragma unroll
  for (int d = 0; d < D_; ++d) acc += xl[d] * w[d*H_ + hh];
  Ubf[((size_t)b*N_ + n)*128 + which*H_ + hh] = (unsigned short)f2bs(acc);
}

// ---------------- K2+K3 fused heterogeneous kernel ----------------
// 3072 blocks x 256 thr. bid%3==2 -> adj path (1024 blocks: 16 rows x 1024 cols);
// else conv path (2048 blocks: 8 series). Interleaved so both co-reside per CU.
__global__ __launch_bounds__(256) void k_fused(const unsigned short* __restrict__ Ubf,
    float* __restrict__ adj, unsigned short* __restrict__ adjbf,
    const float* __restrict__ x, const float4* __restrict__ wT,
    const float* __restrict__ fb1, const float* __restrict__ gb1,
    const float* __restrict__ fb2, const float* __restrict__ gb2,
    const float* __restrict__ fb3, const float* __restrict__ gb3,
    float* __restrict__ h, unsigned short* __restrict__ zbT)
{
  __shared__ __align__(16) char smem[26624];
  int bid = blockIdx.x;
  int grp = bid / 3, sl = bid - grp*3;
  int tid = threadIdx.x;

  if (sl == 2) {
    // ================= adj path: block = 16 rows x 1024 cols =================
    int aidx = grp;                      // 0..1023
    int b  = aidx & 15;
    int n0 = (aidx >> 4) * 16;           // 0..1008
    float (*rsum)[16] = (float(*)[16])smem;          // [4][16]
    float* scrbase = (float*)(smem + 256);           // 4 waves x 1152 floats
    int w = tid >> 6, l = tid & 63;
    int wc = w;
    int l15 = l & 15, lg = l >> 4;
    const unsigned short* Ub = Ubf + (size_t)b*N_*128;

    bf16x8 afr[4];
    #pragma unroll
    for (int kc = 0; kc < 4; ++kc)
      afr[kc] = *reinterpret_cast<const bf16x8*>(Ub + (size_t)(n0 + l15)*128 + 32*kc + 8*lg);

    f32x4 acc[16];
    #pragma unroll
    for (int ct = 0; ct < 16; ++ct) acc[ct] = (f32x4){0.f,0.f,0.f,0.f};

    #pragma unroll
    for (int ct = 0; ct < 16; ++ct) {
      const unsigned short* Um = Ub + (size_t)(256*wc + 16*ct + l15)*128;
      #pragma unroll
      for (int kc = 0; kc < 4; ++kc) {
        int ks = (32*kc + 8*lg + 64) & 127;
        bf16x8 bfr = *reinterpret_cast<const bf16x8*>(Um + ks);
        acc[ct] = MFMA16(afr[kc], bfr, acc[ct]);
      }
    }

    float rs[4] = {0.f,0.f,0.f,0.f};
    #pragma unroll
    for (int ct = 0; ct < 16; ++ct) {
      #pragma unroll
      for (int r = 0; r < 4; ++r) {
        float e = __expf(d_tanhf(acc[ct][r]));
        acc[ct][r] = e;
        rs[r] += e;
      }
    }
    #pragma unroll
    for (int r = 0; r < 4; ++r) {
      float s = rs[r];
      s += __shfl_xor(s, 1); s += __shfl_xor(s, 2);
      s += __shfl_xor(s, 4); s += __shfl_xor(s, 8);
      rs[r] = s;
    }
    if (l15 == 0) {
      #pragma unroll
      for (int r = 0; r < 4; ++r)
        rsum[wc][4*lg + r] = rs[r];
    }
    __syncthreads();
    float inv[4];
    #pragma unroll
    for (int r = 0; r < 4; ++r) {
      int row = 4*lg + r;
      inv[r] = 1.0f / (rsum[0][row] + rsum[1][row] + rsum[2][row] + rsum[3][row]);
    }

    float* myscr = scrbase + w*1152;
    size_t rowbase = (size_t)b*N_ + n0;
    #pragma unroll
    for (int chunk = 0; chunk < 4; ++chunk) {
      #pragma unroll
      for (int cc = 0; cc < 4; ++cc) {
        int ct = chunk*4 + cc;
        #pragma unroll
        for (int r = 0; r < 4; ++r)
          myscr[(4*lg + r)*72 + 16*cc + l15] = acc[ct][r] * inv[r];
      }
      #pragma unroll
      for (int j = 0; j < 4; ++j) {
        int row = (l >> 3) + 8*(j >> 1);
        int c4  = (l & 7) + 8*(j & 1);
        f32x4 v = *reinterpret_cast<const f32x4*>(&myscr[row*72 + c4*4]);
        int m = 256*wc + 64*chunk + c4*4;
        __builtin_nontemporal_store(v, reinterpret_cast<f32x4*>(&adj[(rowbase + row)*N_ + m]));
      }
      #pragma unroll
      for (int j = 0; j < 4; ++j) {
        int row = (l >> 4) + 4*j;
        int cu2 = l & 15;
        const float* p = &myscr[row*72 + cu2*4];
        uint2 pv; pv.x = packbf(p[0], p[1]); pv.y = packbf(p[2], p[3]);
        int m = 256*wc + 64*chunk + cu2*4;
        *reinterpret_cast<uint2*>(&adjbf[(rowbase + row)*N_ + m]) = pv;
      }
    }
    return;
  }

  // ================= conv path: 8 series/block =================
  int cidx = grp*2 + sl;                 // 0..2047
  int b  = cidx & 15;
  int n0 = (cidx >> 4) * 8;
  float (*xs)[15][32] = (float(*)[15][32])smem;               // 15360 B
  float (*y1)[7][32]  = (float(*)[7][32])(smem + 15360);      //  7168 B
  float (*y2)[3][32]  = (float(*)[3][32])(smem + 22528);      //  3072 B

  for (int l = tid; l < 960; l += 256) {
    int t = l >> 6, r = l & 63;
    int nl = r >> 3, d4 = r & 7;
    float4 v = reinterpret_cast<const float4*>(x)[(((size_t)b*T_ + 49 + t)*N_ + n0 + nl)*8 + d4];
    *reinterpret_cast<float4*>(&xs[nl][t][d4*4]) = v;
  }
  __syncthreads();

  int s = tid >> 5, c = tid & 31;
  const float4* wf1 = wT + 0*768 + c;
  const float4* wg1 = wT + 1*768 + c;
  const float4* wf2 = wT + 2*768 + c;
  const float4* wg2 = wT + 3*768 + c;
  const float4* wf3 = wT + 4*768 + c;
  const float4* wg3 = wT + 5*768 + c;

  float af[7], ag[7];
  {
    float bf = fb1[c], bg = gb1[c];
    #pragma unroll
    for (int p=0;p<7;++p){ af[p]=bf; ag[p]=bg; }
  }
  for (int ic4 = 0; ic4 < 8; ++ic4) {
    float wfl[12], wgl[12];
    #pragma unroll
    for (int q=0;q<3;++q){
      float4 a = wf1[(ic4*3+q)*32];
      float4 g = wg1[(ic4*3+q)*32];
      wfl[q*4+0]=a.x; wfl[q*4+1]=a.y; wfl[q*4+2]=a.z; wfl[q*4+3]=a.w;
      wgl[q*4+0]=g.x; wgl[q*4+1]=g.y; wgl[q*4+2]=g.z; wgl[q*4+3]=g.w;
    }
    #pragma unroll
    for (int p = 0; p < 7; ++p) {
      float4 xa = *reinterpret_cast<const float4*>(&xs[s][2*p+0][ic4*4]);
      float4 xb = *reinterpret_cast<const float4*>(&xs[s][2*p+1][ic4*4]);
      float4 xc = *reinterpret_cast<const float4*>(&xs[s][2*p+2][ic4*4]);
      af[p] += xa.x*wfl[0] + xb.x*wfl[1] + xc.x*wfl[2]
             + xa.y*wfl[3] + xb.y*wfl[4] + xc.y*wfl[5]
             + xa.z*wfl[6] + xb.z*wfl[7] + xc.z*wfl[8]
             + xa.w*wfl[9] + xb.w*wfl[10]+ xc.w*wfl[11];
      ag[p] += xa.x*wgl[0] + xb.x*wgl[1] + xc.x*wgl[2]
             + xa.y*wgl[3] + xb.y*wgl[4] + xc.y*wgl[5]
             + xa.z*wgl[6] + xb.z*wgl[7] + xc.z*wgl[8]
             + xa.w*wgl[9] + xb.w*wgl[10]+ xc.w*wgl[11];
    }
  }
  #pragma unroll
  for (int p=0;p<7;++p) y1[s][p][c] = d_tanhf(af[p]) * d_sigmf(ag[p]);
  __syncthreads();

  float af2[3], ag2[3];
  {
    float bf = fb2[c], bg = gb2[c];
    #pragma unroll
    for (int r=0;r<3;++r){ af2[r]=bf; ag2[r]=bg; }
  }
  for (int ic4 = 0; ic4 < 8; ++ic4) {
    float wfl[12], wgl[12];
    #pragma unroll
    for (int q=0;q<3;++q){
      float4 a = wf2[(ic4*3+q)*32];
      float4 g = wg2[(ic4*3+q)*32];
      wfl[q*4+0]=a.x; wfl[q*4+1]=a.y; wfl[q*4+2]=a.z; wfl[q*4+3]=a.w;
      wgl[q*4+0]=g.x; wgl[q*4+1]=g.y; wgl[q*4+2]=g.z; wgl[q*4+3]=g.w;
    }
    #pragma unroll
    for (int r = 0; r < 3; ++r) {
      float4 xa = *reinterpret_cast<const float4*>(&y1[s][2*r+0][ic4*4]);
      float4 xb = *reinterpret_cast<const float4*>(&y1[s][2*r+1][ic4*4]);
      float4 xc = *reinterpret_cast<const float4*>(&y1[s][2*r+2][ic4*4]);
      af2[r] += xa.x*wfl[0] + xb.x*wfl[1] + xc.x*wfl[2]
              + xa.y*wfl[3] + xb.y*wfl[4] + xc.y*wfl[5]
              + xa.z*wfl[6] + xb.z*wfl[7] + xc.z*wfl[8]
              + xa.w*wfl[9] + xb.w*wfl[10]+ xc.w*wfl[11];
      ag2[r] += xa.x*wgl[0] + xb.x*wgl[1] + xc.x*wgl[2]
              + xa.y*wgl[3] + xb.y*wgl[4] + xc.y*wgl[5]
              + xa.z*wgl[6] + xb.z*wgl[7] + xc.z*wgl[8]
              + xa.w*wgl[9] + xb.w*wgl[10]+ xc.w*wgl[11];
    }
  }
  #pragma unroll
  for (int r=0;r<3;++r) y2[s][r][c] = d_tanhf(af2[r]) * d_sigmf(ag2[r]);
  __syncthreads();

  float af3 = fb3[c], ag3 = gb3[c];
  for (int ic4 = 0; ic4 < 8; ++ic4) {
    float wfl[12], wgl[12];
    #pragma unroll
    for (int q=0;q<3;++q){
      float4 a = wf3[(ic4*3+q)*32];
      float4 g = wg3[(ic4*3+q)*32];
      wfl[q*4+0]=a.x; wfl[q*4+1]=a.y; wfl[q*4+2]=a.z; wfl[q*4+3]=a.w;
      wgl[q*4+0]=g.x; wgl[q*4+1]=g.y; wgl[q*4+2]=g.z; wgl[q*4+3]=g.w;
    }
    float4 xa = *reinterpret_cast<const float4*>(&y2[s][0][ic4*4]);
    float4 xb = *reinterpret_cast<const float4*>(&y2[s][1][ic4*4]);
    float4 xc = *reinterpret_cast<const float4*>(&y2[s][2][ic4*4]);
    af3 += xa.x*wfl[0] + xb.x*wfl[1] + xc.x*wfl[2]
         + xa.y*wfl[3] + xb.y*wfl[4] + xc.y*wfl[5]
         + xa.z*wfl[6] + xb.z*wfl[7] + xc.z*wfl[8]
         + xa.w*wfl[9] + xb.w*wfl[10]+ xc.w*wfl[11];
    ag3 += xa.x*wgl[0] + xb.x*wgl[1] + xc.x*wgl[2]
         + xa.y*wgl[3] + xb.y*wgl[4] + xc.y*wgl[5]
         + xa.z*wgl[6] + xb.z*wgl[7] + xc.z*wgl[8]
         + xa.w*wgl[9] + xb.w*wgl[10]+ xc.w*wgl[11];
  }
  float hv = d_tanhf(af3) * d_sigmf(ag3);
  int n = n0 + s;
  h[((size_t)b*N_ + n)*C_ + c] = hv;
  zbT[((size_t)b*32 + c)*N_ + n] = (unsigned short)f2bs(hv);
}

// ---------------- K4: propm, 512 thr, 4-way K-split, 2 row-groups sharing Z-frags ----------------
__global__ __launch_bounds__(512) void k_propm_bf(const unsigned short* __restrict__ adjbf,
    const unsigned short* __restrict__ zbT, const float* __restrict__ h,
    const float* __restrict__ zin, float* __restrict__ zout,
    unsigned short* __restrict__ zbTout)
{
  __shared__ float red[2][3][2][16][17];
  int b = blockIdx.x & 15;
  int gg = blockIdx.x >> 4;
  int tid = threadIdx.x;
  int w = tid >> 6, l = tid & 63;
  int wk = w >> 1, wc = w & 1;
  int l15 = l & 15, lg = l >> 4;
  int n_base = gg*32;

  const unsigned short* A0 = adjbf + ((size_t)b*N_ + n_base + l15)*N_ + wk*256;
  const unsigned short* A1 = A0 + (size_t)16*N_;
  const unsigned short* Z  = zbT + ((size_t)b*32 + 16*wc + l15)*N_ + wk*256;

  f32x4 acc0 = {0.f,0.f,0.f,0.f}, acc1 = {0.f,0.f,0.f,0.f};
  #pragma unroll
  for (int kc = 0; kc < 8; ++kc) {
    int k0 = 32*kc + 8*lg;
    bf16x8 zf = *reinterpret_cast<const bf16x8*>(Z + k0);
    bf16x8 a0 = *reinterpret_cast<const bf16x8*>(A0 + k0);
    bf16x8 a1 = *reinterpret_cast<const bf16x8*>(A1 + k0);
    acc0 = MFMA16(a0, zf, acc0);
    acc1 = MFMA16(a1, zf, acc1);
  }

  if (wk > 0) {
    #pragma unroll
    for (int r = 0; r < 4; ++r) {
      red[0][wk-1][wc][4*lg + r][l15] = acc0[r];
      red[1][wk-1][wc][4*lg + r][l15] = acc1[r];
    }
  }
  __syncthreads();
  if (wk == 0) {
    int c = 16*wc + l15;
    #pragma unroll
    for (int gi = 0; gi < 2; ++gi) {
      f32x4 acc = gi ? acc1 : acc0;
      float v[4];
      #pragma unroll
      for (int r = 0; r < 4; ++r) {
        int row = 4*lg + r;
        float a = acc[r] + red[gi][0][wc][row][l15]
                         + red[gi][1][wc][row][l15]
                         + red[gi][2][wc][row][l15];
        int n = n_base + gi*16 + row;
        size_t idx = ((size_t)b*N_ + n)*32 + c;
        v[r] = 0.1f*h[idx] + 0.45f*zin[idx] + 0.45f*a;
        zout[idx] = v[r];
      }
      uint2 pv;
      pv.x = packbf(v[0], v[1]);
      pv.y = packbf(v[2], v[3]);
      *reinterpret_cast<uint2*>(zbTout + ((size_t)b*32 + c)*N_ + n_base + gi*16 + 4*lg) = pv;
    }
  }
}

// ---------------- K4-last: final iteration fused with out = relu(z) @ wo + bo ----------------
__global__ __launch_bounds__(512) void k_propm_bf_last(const unsigned short* __restrict__ adjbf,
    const unsigned short* __restrict__ zbT, const float* __restrict__ h,
    const float* __restrict__ zin, const float* __restrict__ wo,
    const float* __restrict__ bo, float* __restrict__ out)
{
  __shared__ float red[2][3][2][16][17];
  __shared__ float zfin[32][33];
  int b = blockIdx.x & 15;
  int gg = blockIdx.x >> 4;
  int tid = threadIdx.x;
  int w = tid >> 6, l = tid & 63;
  int wk = w >> 1, wc = w & 1;
  int l15 = l & 15, lg = l >> 4;
  int n_base = gg*32;

  const unsigned short* A0 = adjbf + ((size_t)b*N_ + n_base + l15)*N_ + wk*256;
  const unsigned short* A1 = A0 + (size_t)16*N_;
  const unsigned short* Z  = zbT + ((size_t)b*32 + 16*wc + l15)*N_ + wk*256;

  f32x4 acc0 = {0.f,0.f,0.f,0.f}, acc1 = {0.f,0.f,0.f,0.f};
  #pragma unroll
  for (int kc = 0; kc < 8; ++kc) {
    int k0 = 32*kc + 8*lg;
    bf16x8 zf = *reinterpret_cast<const bf16x8*>(Z + k0);
    bf16x8 a0 = *reinterpret_cast<const bf16x8*>(A0 + k0);
    bf16x8 a1 = *reinterpret_cast<const bf16x8*>(A1 + k0);
    acc0 = MFMA16(a0, zf, acc0);
    acc1 = MFMA16(a1, zf, acc1);
  }

  if (wk > 0) {
    #pragma unroll
    for (int r = 0; r < 4; ++r) {
      red[0][wk-1][wc][4*lg + r][l15] = acc0[r];
      red[1][wk-1][wc][4*lg + r][l15] = acc1[r];
    }
  }
  __syncthreads();
  if (wk == 0) {
    int c = 16*wc + l15;
    #pragma unroll
    for (int gi = 0; gi < 2; ++gi) {
      f32x4 acc = gi ? acc1 : acc0;
      #pragma unroll
      for (int r = 0; r < 4; ++r) {
        int row = 4*lg + r;
        float a = acc[r] + red[gi][0][wc][row][l15]
                         + red[gi][1][wc][row][l15]
                         + red[gi][2][wc][row][l15];
        int n = n_base + gi*16 + row;
        size_t idx = ((size_t)b*N_ + n)*32 + c;
        float v = 0.1f*h[idx] + 0.45f*zin[idx] + 0.45f*a;
        zfin[gi*16 + row][c] = fmaxf(v, 0.f);
      }
    }
  }
  __syncthreads();
  if (tid < 384) {
    int n = tid / 12, o = tid - n*12;
    float acc2 = bo[o];
    #pragma unroll
    for (int cc = 0; cc < 32; ++cc) acc2 += zfin[n][cc] * wo[cc*O_ + o];
    out[((size_t)b*N_ + n_base + n)*O_ + o] = acc2;
  }
}

extern "C" void kernel_launch(void* const* d_in, const int* in_sizes, int n_in,
                              void* d_out, int out_size, void* d_ws, size_t ws_size,
                              hipStream_t stream)
{
  const float* x   = (const float*)d_in[0];
  const float* w1  = (const float*)d_in[1];
  const float* b1  = (const float*)d_in[2];
  const float* w2  = (const float*)d_in[3];
  const float* b2  = (const float*)d_in[4];
  const float* fw1 = (const float*)d_in[5];  const float* fb1 = (const float*)d_in[6];
  const float* gw1 = (const float*)d_in[7];  const float* gb1 = (const float*)d_in[8];
  const float* fw2 = (const float*)d_in[9];  const float* fb2 = (const float*)d_in[10];
  const float* gw2 = (const float*)d_in[11]; const float* gb2 = (const float*)d_in[12];
  const float* fw3 = (const float*)d_in[13]; const float* fb3 = (const float*)d_in[14];
  const float* gw3 = (const float*)d_in[15]; const float* gb3 = (const float*)d_in[16];
  const float* wo  = (const float*)d_in[17]; const float* bo  = (const float*)d_in[18];

  float* out = (float*)d_out;
  float* adj = out + (size_t)B_*N_*O_;

  char* ws = (char*)d_ws;
  unsigned short* Ubf  = (unsigned short*)ws;                       // 4 MB
  float* h             = (float*)(ws + (4ull<<20));                 // 2 MB
  float* z0            = (float*)(ws + (6ull<<20));                 // 2 MB
  float* z1            = (float*)(ws + (8ull<<20));                 // 2 MB
  unsigned short* zbT0 = (unsigned short*)(ws + (10ull<<20));       // 1 MB
  unsigned short* zbT1 = (unsigned short*)(ws + (11ull<<20));       // 1 MB
  unsigned short* adjbf= (unsigned short*)(ws + (12ull<<20));       // 32 MB
  float4* wT           = (float4*)(ws + (44ull<<20));               // 72 KB

  k_wt<<<18, 256, 0, stream>>>(fw1, gw1, fw2, gw2, fw3, gw3, wT);
  k_u<<<B_*N_, 128, 0, stream>>>(x, w1, b1, w2, b2, Ubf);
  k_fused<<<3072, 256, 0, stream>>>(Ubf, adj, adjbf, x, wT,
                                    fb1, gb1, fb2, gb2, fb3, gb3, h, zbT0);

  const float* zi = h;
  const unsigned short* zbi = zbT0;
  float* zfbuf[2] = {z0, z1};
  unsigned short* zbbuf[2] = {zbT1, zbT0};
  for (int it = 0; it < 9; ++it) {
    float* zo = zfbuf[it & 1];
    unsigned short* zbo = zbbuf[it & 1];
    k_propm_bf<<<B_*32, 512, 0, stream>>>(adjbf, zbi, h, zi, zo, zbo);
    zi = zo; zbi = zbo;
  }
  k_propm_bf_last<<<B_*32, 512, 0, stream>>>(adjbf, zbi, h, zi, wo, bo, out);
}

// Round 19
// 247.611 us; speedup vs baseline: 1.0253x; 1.0253x over previous
//
#include <hip/hip_runtime.h>
#include <hip/hip_bf16.h>
#include <cstddef>

#define B_ 16
#define T_ 64
#define N_ 1024
#define D_ 32
#define H_ 64
#define C_ 32
#define O_ 12

typedef __attribute__((ext_vector_type(8))) short bf16x8;
typedef __attribute__((ext_vector_type(4))) float f32x4;
#define MFMA16(a,b,c) __builtin_amdgcn_mfma_f32_16x16x32_bf16(a,b,c,0,0,0)

__device__ __forceinline__ float d_tanhf(float v){ float e = __expf(2.f*v); return 1.f - 2.f/(e + 1.f); }
__device__ __forceinline__ float d_sigmf(float v){ return 1.f/(1.f + __expf(-v)); }
__device__ __forceinline__ short f2bs(float f){
  __hip_bfloat16 h = __float2bfloat16(f);
  union { __hip_bfloat16 b; short s; } u; u.b = h; return u.s;
}
__device__ __forceinline__ unsigned int packbf(float lo, float hi){
  return (unsigned int)(unsigned short)f2bs(lo) | ((unsigned int)(unsigned short)f2bs(hi) << 16);
}

// ---------------- K1: Ubf[b,n,0:64]=bf16(m1), [64:128]=bf16(m2) ----------------
__global__ __launch_bounds__(128) void k_u(const float* __restrict__ x,
    const float* __restrict__ w1, const float* __restrict__ b1,
    const float* __restrict__ w2, const float* __restrict__ b2,
    unsigned short* __restrict__ Ubf)
{
  int row = blockIdx.x;
  int b = row & 15, n = row >> 4;
  int t = threadIdx.x;
  int hh = t & (H_-1), which = t >> 6;
  __shared__ float xl[D_];
  if (t < D_) xl[t] = x[(((size_t)b*T_ + (T_-1))*N_ + n)*D_ + t];
  __syncthreads();
  const float* w  = which ? w2 : w1;
  const float* bi = which ? b2 : b1;
  float acc = bi[hh];
  #pragma unroll
  for (int d = 0; d < D_; ++d) acc += xl[d] * w[d*H_ + hh];
  Ubf[((size_t)b*N_ + n)*128 + which*H_ + hh] = (unsigned short)f2bs(acc);
}

// ---------------- K2: adj = softmax(tanh(S)); wave = 16 rows x 256 cols (acc[16]) ----------------
// Block: 512 thr = 8 waves (wr x wc) = 32 rows x 1024 cols. Grid 512.
// Epilogue: per-wave LDS transpose -> coalesced f32x4 (adj) + uint2 (adjbf) stores.
__global__ __launch_bounds__(512, 4) void k_adj(const unsigned short* __restrict__ Ubf,
                                                float* __restrict__ adj,
                                                unsigned short* __restrict__ adjbf)
{
  __shared__ float rsum[4][32];
  __shared__ float scr[8][16*72];    // 36.9 KB per-wave transpose scratch
  int b  = blockIdx.x & 15;
  int n0 = (blockIdx.x >> 4) * 32;
  int tid = threadIdx.x;
  int w = tid >> 6, l = tid & 63;
  int wr = w >> 2, wc = w & 3;       // wr: row half (16 rows), wc: col quarter (256 cols)
  int l15 = l & 15, lg = l >> 4;
  const unsigned short* Ub = Ubf + (size_t)b*N_*128;

  bf16x8 afr[4];
  #pragma unroll
  for (int kc = 0; kc < 4; ++kc)
    afr[kc] = *reinterpret_cast<const bf16x8*>(Ub + (size_t)(n0 + 16*wr + l15)*128 + 32*kc + 8*lg);

  f32x4 acc[16];
  #pragma unroll
  for (int ct = 0; ct < 16; ++ct) acc[ct] = (f32x4){0.f,0.f,0.f,0.f};

  #pragma unroll
  for (int ct = 0; ct < 16; ++ct) {
    const unsigned short* Um = Ub + (size_t)(256*wc + 16*ct + l15)*128;
    #pragma unroll
    for (int kc = 0; kc < 4; ++kc) {
      int ks = (32*kc + 8*lg + 64) & 127;   // swapped-halves B operand
      bf16x8 bfr = *reinterpret_cast<const bf16x8*>(Um + ks);
      acc[ct] = MFMA16(afr[kc], bfr, acc[ct]);
    }
  }

  float rs[4] = {0.f,0.f,0.f,0.f};
  #pragma unroll
  for (int ct = 0; ct < 16; ++ct) {
    #pragma unroll
    for (int r = 0; r < 4; ++r) {
      float e = __expf(d_tanhf(acc[ct][r]));
      acc[ct][r] = e;
      rs[r] += e;
    }
  }
  #pragma unroll
  for (int r = 0; r < 4; ++r) {
    float s = rs[r];
    s += __shfl_xor(s, 1); s += __shfl_xor(s, 2);
    s += __shfl_xor(s, 4); s += __shfl_xor(s, 8);
    rs[r] = s;
  }
  if (l15 == 0) {
    #pragma unroll
    for (int r = 0; r < 4; ++r)
      rsum[wc][16*wr + 4*lg + r] = rs[r];
  }
  __syncthreads();
  float inv[4];
  #pragma unroll
  for (int r = 0; r < 4; ++r) {
    int row = 16*wr + 4*lg + r;
    inv[r] = 1.0f / (rsum[0][row] + rsum[1][row] + rsum[2][row] + rsum[3][row]);
  }

  float* myscr = scr[w];
  size_t rowbase = (size_t)b*N_ + n0 + 16*wr;
  #pragma unroll
  for (int chunk = 0; chunk < 4; ++chunk) {
    #pragma unroll
    for (int cc = 0; cc < 4; ++cc) {
      int ct = chunk*4 + cc;
      #pragma unroll
      for (int r = 0; r < 4; ++r)
        myscr[(4*lg + r)*72 + 16*cc + l15] = acc[ct][r] * inv[r];
    }
    #pragma unroll
    for (int j = 0; j < 4; ++j) {
      int row = (l >> 3) + 8*(j >> 1);
      int c4  = (l & 7) + 8*(j & 1);
      f32x4 v = *reinterpret_cast<const f32x4*>(&myscr[row*72 + c4*4]);
      int m = 256*wc + 64*chunk + c4*4;
      __builtin_nontemporal_store(v, reinterpret_cast<f32x4*>(&adj[(rowbase + row)*N_ + m]));
    }
    #pragma unroll
    for (int j = 0; j < 4; ++j) {
      int row = (l >> 4) + 4*j;
      int cu2 = l & 15;
      const float* p = &myscr[row*72 + cu2*4];
      uint2 pv; pv.x = packbf(p[0], p[1]); pv.y = packbf(p[2], p[3]);
      int m = 256*wc + 64*chunk + cu2*4;
      *reinterpret_cast<uint2*>(&adjbf[(rowbase + row)*N_ + m]) = pv;
    }
  }
}

// ---------------- K3: gated dilated convs (R7-proven), 256 thr, 8 series, LDS weights ----------------
__global__ __launch_bounds__(256) void k_conv(const float* __restrict__ x,
    const float* __restrict__ fw1,const float* __restrict__ fb1,const float* __restrict__ gw1,const float* __restrict__ gb1,
    const float* __restrict__ fw2,const float* __restrict__ fb2,const float* __restrict__ gw2,const float* __restrict__ gb2,
    const float* __restrict__ fw3,const float* __restrict__ fb3,const float* __restrict__ gw3,const float* __restrict__ gb3,
    float* __restrict__ h, unsigned short* __restrict__ zbT)
{
  __shared__ float xs[8][15][32];
  __shared__ float y1[8][7][32];
  __shared__ float y2[8][3][32];
  __shared__ float4 wl4[1600];
  int tid = threadIdx.x;
  int b  = blockIdx.x & 15;
  int n0 = (blockIdx.x >> 4) * 8;

  for (int l = tid; l < 960; l += 256) {
    int t = l >> 6, r = l & 63;
    int nl = r >> 3, d4 = r & 7;
    float4 v = reinterpret_cast<const float4*>(x)[(((size_t)b*T_ + 49 + t)*N_ + n0 + nl)*8 + d4];
    *reinterpret_cast<float4*>(&xs[nl][t][d4*4]) = v;
  }
  for (int l = tid; l < 768; l += 256) {
    int cc = l / 24, f4 = l - cc*24;
    wl4[cc*25 + f4]       = reinterpret_cast<const float4*>(fw1)[l];
    wl4[800 + cc*25 + f4] = reinterpret_cast<const float4*>(gw1)[l];
  }
  __syncthreads();

  int s = tid >> 5, c = tid & 31;

  float af[7], ag[7];
  {
    float bf = fb1[c], bg = gb1[c];
    #pragma unroll
    for (int p=0;p<7;++p){ af[p]=bf; ag[p]=bg; }
  }
  for (int ic4 = 0; ic4 < 8; ++ic4) {
    float wfl[12], wgl[12];
    {
      const float4* fp = wl4 + c*25 + ic4*3;
      const float4* gp = wl4 + 800 + c*25 + ic4*3;
      #pragma unroll
      for (int q=0;q<3;++q){
        float4 a = fp[q], g = gp[q];
        wfl[q*4+0]=a.x; wfl[q*4+1]=a.y; wfl[q*4+2]=a.z; wfl[q*4+3]=a.w;
        wgl[q*4+0]=g.x; wgl[q*4+1]=g.y; wgl[q*4+2]=g.z; wgl[q*4+3]=g.w;
      }
    }
    #pragma unroll
    for (int p = 0; p < 7; ++p) {
      float4 xa = *reinterpret_cast<const float4*>(&xs[s][2*p+0][ic4*4]);
      float4 xb = *reinterpret_cast<const float4*>(&xs[s][2*p+1][ic4*4]);
      float4 xc = *reinterpret_cast<const float4*>(&xs[s][2*p+2][ic4*4]);
      af[p] += xa.x*wfl[0] + xb.x*wfl[1] + xc.x*wfl[2]
             + xa.y*wfl[3] + xb.y*wfl[4] + xc.y*wfl[5]
             + xa.z*wfl[6] + xb.z*wfl[7] + xc.z*wfl[8]
             + xa.w*wfl[9] + xb.w*wfl[10]+ xc.w*wfl[11];
      ag[p] += xa.x*wgl[0] + xb.x*wgl[1] + xc.x*wgl[2]
             + xa.y*wgl[3] + xb.y*wgl[4] + xc.y*wgl[5]
             + xa.z*wgl[6] + xb.z*wgl[7] + xc.z*wgl[8]
             + xa.w*wgl[9] + xb.w*wgl[10]+ xc.w*wgl[11];
    }
  }
  #pragma unroll
  for (int p=0;p<7;++p) y1[s][p][c] = d_tanhf(af[p]) * d_sigmf(ag[p]);
  __syncthreads();

  for (int l = tid; l < 768; l += 256) {
    int cc = l / 24, f4 = l - cc*24;
    wl4[cc*25 + f4]       = reinterpret_cast<const float4*>(fw2)[l];
    wl4[800 + cc*25 + f4] = reinterpret_cast<const float4*>(gw2)[l];
  }
  __syncthreads();

  float af2[3], ag2[3];
  {
    float bf = fb2[c], bg = gb2[c];
    #pragma unroll
    for (int r=0;r<3;++r){ af2[r]=bf; ag2[r]=bg; }
  }
  for (int ic4 = 0; ic4 < 8; ++ic4) {
    float wfl[12], wgl[12];
    {
      const float4* fp = wl4 + c*25 + ic4*3;
      const float4* gp = wl4 + 800 + c*25 + ic4*3;
      #pragma unroll
      for (int q=0;q<3;++q){
        float4 a = fp[q], g = gp[q];
        wfl[q*4+0]=a.x; wfl[q*4+1]=a.y; wfl[q*4+2]=a.z; wfl[q*4+3]=a.w;
        wgl[q*4+0]=g.x; wgl[q*4+1]=g.y; wgl[q*4+2]=g.z; wgl[q*4+3]=g.w;
      }
    }
    #pragma unroll
    for (int r = 0; r < 3; ++r) {
      float4 xa = *reinterpret_cast<const float4*>(&y1[s][2*r+0][ic4*4]);
      float4 xb = *reinterpret_cast<const float4*>(&y1[s][2*r+1][ic4*4]);
      float4 xc = *reinterpret_cast<const float4*>(&y1[s][2*r+2][ic4*4]);
      af2[r] += xa.x*wfl[0] + xb.x*wfl[1] + xc.x*wfl[2]
              + xa.y*wfl[3] + xb.y*wfl[4] + xc.y*wfl[5]
              + xa.z*wfl[6] + xb.z*wfl[7] + xc.z*wfl[8]
              + xa.w*wfl[9] + xb.w*wfl[10]+ xc.w*wfl[11];
      ag2[r] += xa.x*wgl[0] + xb.x*wgl[1] + xc.x*wgl[2]
              + xa.y*wgl[3] + xb.y*wgl[4] + xc.y*wgl[5]
              + xa.z*wgl[6] + xb.z*wgl[7] + xc.z*wgl[8]
              + xa.w*wgl[9] + xb.w*wgl[10]+ xc.w*wgl[11];
    }
  }
  #pragma unroll
  for (int r=0;r<3;++r) y2[s][r][c] = d_tanhf(af2[r]) * d_sigmf(ag2[r]);
  __syncthreads();

  for (int l = tid; l < 768; l += 256) {
    int cc = l / 24, f4 = l - cc*24;
    wl4[cc*25 + f4]       = reinterpret_cast<const float4*>(fw3)[l];
    wl4[800 + cc*25 + f4] = reinterpret_cast<const float4*>(gw3)[l];
  }
  __syncthreads();

  float af3 = fb3[c], ag3 = gb3[c];
  for (int ic4 = 0; ic4 < 8; ++ic4) {
    float wfl[12], wgl[12];
    {
      const float4* fp = wl4 + c*25 + ic4*3;
      const float4* gp = wl4 + 800 + c*25 + ic4*3;
      #pragma unroll
      for (int q=0;q<3;++q){
        float4 a = fp[q], g = gp[q];
        wfl[q*4+0]=a.x; wfl[q*4+1]=a.y; wfl[q*4+2]=a.z; wfl[q*4+3]=a.w;
        wgl[q*4+0]=g.x; wgl[q*4+1]=g.y; wgl[q*4+2]=g.z; wgl[q*4+3]=g.w;
      }
    }
    float4 xa = *reinterpret_cast<const float4*>(&y2[s][0][ic4*4]);
    float4 xb = *reinterpret_cast<const float4*>(&y2[s][1][ic4*4]);
    float4 xc = *reinterpret_cast<const float4*>(&y2[s][2][ic4*4]);
    af3 += xa.x*wfl[0] + xb.x*wfl[1] + xc.x*wfl[2]
         + xa.y*wfl[3] + xb.y*wfl[4] + xc.y*wfl[5]
         + xa.z*wfl[6] + xb.z*wfl[7] + xc.z*wfl[8]
         + xa.w*wfl[9] + xb.w*wfl[10]+ xc.w*wfl[11];
    ag3 += xa.x*wgl[0] + xb.x*wgl[1] + xc.x*wgl[2]
         + xa.y*wgl[3] + xb.y*wgl[4] + xc.y*wgl[5]
         + xa.z*wgl[6] + xb.z*wgl[7] + xc.z*wgl[8]
         + xa.w*wgl[9] + xb.w*wgl[10]+ xc.w*wgl[11];
  }
  float hv = d_tanhf(af3) * d_sigmf(ag3);
  int n = n0 + s;
  h[((size_t)b*N_ + n)*C_ + c] = hv;
  zbT[((size_t)b*32 + c)*N_ + n] = (unsigned short)f2bs(hv);
}

// ---------------- K4: propm, 512 thr, 4-way K-split, 2 row-groups sharing Z-frags ----------------
__global__ __launch_bounds__(512) void k_propm_bf(const unsigned short* __restrict__ adjbf,
    const unsigned short* __restrict__ zbT, const float* __restrict__ h,
    const float* __restrict__ zin, float* __restrict__ zout,
    unsigned short* __restrict__ zbTout)
{
  __shared__ float red[2][3][2][16][17];
  int b = blockIdx.x & 15;
  int gg = blockIdx.x >> 4;
  int tid = threadIdx.x;
  int w = tid >> 6, l = tid & 63;
  int wk = w >> 1, wc = w & 1;
  int l15 = l & 15, lg = l >> 4;
  int n_base = gg*32;

  const unsigned short* A0 = adjbf + ((size_t)b*N_ + n_base + l15)*N_ + wk*256;
  const unsigned short* A1 = A0 + (size_t)16*N_;
  const unsigned short* Z  = zbT + ((size_t)b*32 + 16*wc + l15)*N_ + wk*256;

  f32x4 acc0 = {0.f,0.f,0.f,0.f}, acc1 = {0.f,0.f,0.f,0.f};
  #pragma unroll
  for (int kc = 0; kc < 8; ++kc) {
    int k0 = 32*kc + 8*lg;
    bf16x8 zf = *reinterpret_cast<const bf16x8*>(Z + k0);
    bf16x8 a0 = *reinterpret_cast<const bf16x8*>(A0 + k0);
    bf16x8 a1 = *reinterpret_cast<const bf16x8*>(A1 + k0);
    acc0 = MFMA16(a0, zf, acc0);
    acc1 = MFMA16(a1, zf, acc1);
  }

  if (wk > 0) {
    #pragma unroll
    for (int r = 0; r < 4; ++r) {
      red[0][wk-1][wc][4*lg + r][l15] = acc0[r];
      red[1][wk-1][wc][4*lg + r][l15] = acc1[r];
    }
  }
  __syncthreads();
  if (wk == 0) {
    int c = 16*wc + l15;
    #pragma unroll
    for (int gi = 0; gi < 2; ++gi) {
      f32x4 acc = gi ? acc1 : acc0;
      float v[4];
      #pragma unroll
      for (int r = 0; r < 4; ++r) {
        int row = 4*lg + r;
        float a = acc[r] + red[gi][0][wc][row][l15]
                         + red[gi][1][wc][row][l15]
                         + red[gi][2][wc][row][l15];
        int n = n_base + gi*16 + row;
        size_t idx = ((size_t)b*N_ + n)*32 + c;
        v[r] = 0.1f*h[idx] + 0.45f*zin[idx] + 0.45f*a;
        zout[idx] = v[r];
      }
      uint2 pv;
      pv.x = packbf(v[0], v[1]);
      pv.y = packbf(v[2], v[3]);
      *reinterpret_cast<uint2*>(zbTout + ((size_t)b*32 + c)*N_ + n_base + gi*16 + 4*lg) = pv;
    }
  }
}

// ---------------- K4-last: final iteration fused with out = relu(z) @ wo + bo ----------------
__global__ __launch_bounds__(512) void k_propm_bf_last(const unsigned short* __restrict__ adjbf,
    const unsigned short* __restrict__ zbT, const float* __restrict__ h,
    const float* __restrict__ zin, const float* __restrict__ wo,
    const float* __restrict__ bo, float* __restrict__ out)
{
  __shared__ float red[2][3][2][16][17];
  __shared__ float zfin[32][33];
  int b = blockIdx.x & 15;
  int gg = blockIdx.x >> 4;
  int tid = threadIdx.x;
  int w = tid >> 6, l = tid & 63;
  int wk = w >> 1, wc = w & 1;
  int l15 = l & 15, lg = l >> 4;
  int n_base = gg*32;

  const unsigned short* A0 = adjbf + ((size_t)b*N_ + n_base + l15)*N_ + wk*256;
  const unsigned short* A1 = A0 + (size_t)16*N_;
  const unsigned short* Z  = zbT + ((size_t)b*32 + 16*wc + l15)*N_ + wk*256;

  f32x4 acc0 = {0.f,0.f,0.f,0.f}, acc1 = {0.f,0.f,0.f,0.f};
  #pragma unroll
  for (int kc = 0; kc < 8; ++kc) {
    int k0 = 32*kc + 8*lg;
    bf16x8 zf = *reinterpret_cast<const bf16x8*>(Z + k0);
    bf16x8 a0 = *reinterpret_cast<const bf16x8*>(A0 + k0);
    bf16x8 a1 = *reinterpret_cast<const bf16x8*>(A1 + k0);
    acc0 = MFMA16(a0, zf, acc0);
    acc1 = MFMA16(a1, zf, acc1);
  }

  if (wk > 0) {
    #pragma unroll
    for (int r = 0; r < 4; ++r) {
      red[0][wk-1][wc][4*lg + r][l15] = acc0[r];
      red[1][wk-1][wc][4*lg + r][l15] = acc1[r];
    }
  }
  __syncthreads();
  if (wk == 0) {
    int c = 16*wc + l15;
    #pragma unroll
    for (int gi = 0; gi < 2; ++gi) {
      f32x4 acc = gi ? acc1 : acc0;
      #pragma unroll
      for (int r = 0; r < 4; ++r) {
        int row = 4*lg + r;
        float a = acc[r] + red[gi][0][wc][row][l15]
                         + red[gi][1][wc][row][l15]
                         + red[gi][2][wc][row][l15];
        int n = n_base + gi*16 + row;
        size_t idx = ((size_t)b*N_ + n)*32 + c;
        float v = 0.1f*h[idx] + 0.45f*zin[idx] + 0.45f*a;
        zfin[gi*16 + row][c] = fmaxf(v, 0.f);
      }
    }
  }
  __syncthreads();
  if (tid < 384) {
    int n = tid / 12, o = tid - n*12;
    float acc2 = bo[o];
    #pragma unroll
    for (int cc = 0; cc < 32; ++cc) acc2 += zfin[n][cc] * wo[cc*O_ + o];
    out[((size_t)b*N_ + n_base + n)*O_ + o] = acc2;
  }
}

extern "C" void kernel_launch(void* const* d_in, const int* in_sizes, int n_in,
                              void* d_out, int out_size, void* d_ws, size_t ws_size,
                              hipStream_t stream)
{
  const float* x   = (const float*)d_in[0];
  const float* w1  = (const float*)d_in[1];
  const float* b1  = (const float*)d_in[2];
  const float* w2  = (const float*)d_in[3];
  const float* b2  = (const float*)d_in[4];
  const float* fw1 = (const float*)d_in[5];  const float* fb1 = (const float*)d_in[6];
  const float* gw1 = (const float*)d_in[7];  const float* gb1 = (const float*)d_in[8];
  const float* fw2 = (const float*)d_in[9];  const float* fb2 = (const float*)d_in[10];
  const float* gw2 = (const float*)d_in[11]; const float* gb2 = (const float*)d_in[12];
  const float* fw3 = (const float*)d_in[13]; const float* fb3 = (const float*)d_in[14];
  const float* gw3 = (const float*)d_in[15]; const float* gb3 = (const float*)d_in[16];
  const float* wo  = (const float*)d_in[17]; const float* bo  = (const float*)d_in[18];

  float* out = (float*)d_out;
  float* adj = out + (size_t)B_*N_*O_;

  char* ws = (char*)d_ws;
  unsigned short* Ubf  = (unsigned short*)ws;                       // 4 MB
  float* h             = (float*)(ws + (4ull<<20));                 // 2 MB
  float* z0            = (float*)(ws + (6ull<<20));                 // 2 MB
  float* z1            = (float*)(ws + (8ull<<20));                 // 2 MB
  unsigned short* zbT0 = (unsigned short*)(ws + (10ull<<20));       // 1 MB
  unsigned short* zbT1 = (unsigned short*)(ws + (11ull<<20));       // 1 MB
  unsigned short* adjbf= (unsigned short*)(ws + (12ull<<20));       // 32 MB

  k_u<<<B_*N_, 128, 0, stream>>>(x, w1, b1, w2, b2, Ubf);
  k_adj<<<B_*32, 512, 0, stream>>>(Ubf, adj, adjbf);
  k_conv<<<B_*N_/8, 256, 0, stream>>>(x, fw1,fb1,gw1,gb1, fw2,fb2,gw2,gb2, fw3,fb3,gw3,gb3, h, zbT0);

  const float* zi = h;
  const unsigned short* zbi = zbT0;
  float* zfbuf[2] = {z0, z1};
  unsigned short* zbbuf[2] = {zbT1, zbT0};
  for (int it = 0; it < 9; ++it) {
    float* zo = zfbuf[it & 1];
    unsigned short* zbo = zbbuf[it & 1];
    k_propm_bf<<<B_*32, 512, 0, stream>>>(adjbf, zbi, h, zi, zo, zbo);
    zi = zo; zbi = zbo;
  }
  k_propm_bf_last<<<B_*32, 512, 0, stream>>>(adjbf, zbi, h, zi, wo, bo, out);
}